// Round 8
// baseline (373.132 us; speedup 1.0000x reference)
//
#include <hip/hip_runtime.h>

// QLSTM recurrence on MI355X — round 10.
// Skeleton = round 9 (232.9 us/dispatch): 4 waves / 4 SIMDs, lane g owns h[g],
// fused-DPP tree, per-wave aq-dot pre-barrier, raw lgkm-only barrier,
// q-affine folded z-weights, tau/owh split, merged-rcp pre-scaled gates,
// spine-priority ordering, x window filler, unroll x4.
//
// Ledger: chain-bound at ~1090 cyc/step. Eliminated by HW: 1-wave (r4),
// flag-poll (r8), issue-trims (r9 neutral). Rejected on paper: packed z-dots
// (distinct scalars per element), x rebalancing (wave64 issue is lane-count
// independent), exp2-partial exchange (net zero across barrier).
//
// Round-10 (last chain items on the exchange segment):
//  - 5-level tree (stop at row_bcast:15): lanes 16-31 hold r0+r1, lanes 48-63
//    hold r2+r3. Both groups dot+write -> 8 partials. -4 DPP adds pre-barrier,
//    +1 pk-add post-barrier.
//  - partA stride padded to 12 floats: both b128 reads 16B-aligned, <=2-way
//    bank alias (free).
//  - both ds_read_b128 issued together at barrier exit.
// Pre-commit: >=232 us => declare structural latency floor next round.

#define B_ 256
#define T_ 512
#define F_ 128
#define H_ 256

#define SC1 1.442695041f    // log2(e)
#define SC2 2.885390082f    // 2*log2(e)
#define ISC2 0.3465735903f  // 1/SC2

typedef float f2 __attribute__((ext_vector_type(2)));

__device__ __forceinline__ float rcp_f(float x)  { return __builtin_amdgcn_rcpf(x); }
__device__ __forceinline__ float exp2_f(float x) { return __builtin_amdgcn_exp2f(x); }

__device__ __forceinline__ f2 mk2(float a, float b) { f2 v; v.x = a; v.y = b; return v; }

__device__ __forceinline__ float rl(float v, int lane) {
    return __int_as_float(__builtin_amdgcn_readlane(__float_as_int(v), lane));
}

// Fused partial 64-lane sum of 4 independent values, 5 levels (through
// row_bcast:15). Valid afterwards: lanes 16-31 hold (row0+row1) sums,
// lanes 48-63 hold (row2+row3) sums. 4 interleaved chains keep every DPP
// consumer >=4 instrs from its producer; s_nop 1 guards the entry hazard.
__device__ __forceinline__ void tree4_5(float& p0, float& p1, float& p2, float& p3) {
    asm volatile(
        "s_nop 1\n\t"
        "v_add_f32_dpp %0, %0, %0 quad_perm:[1,0,3,2] row_mask:0xf bank_mask:0xf\n\t"
        "v_add_f32_dpp %1, %1, %1 quad_perm:[1,0,3,2] row_mask:0xf bank_mask:0xf\n\t"
        "v_add_f32_dpp %2, %2, %2 quad_perm:[1,0,3,2] row_mask:0xf bank_mask:0xf\n\t"
        "v_add_f32_dpp %3, %3, %3 quad_perm:[1,0,3,2] row_mask:0xf bank_mask:0xf\n\t"
        "v_add_f32_dpp %0, %0, %0 quad_perm:[2,3,0,1] row_mask:0xf bank_mask:0xf\n\t"
        "v_add_f32_dpp %1, %1, %1 quad_perm:[2,3,0,1] row_mask:0xf bank_mask:0xf\n\t"
        "v_add_f32_dpp %2, %2, %2 quad_perm:[2,3,0,1] row_mask:0xf bank_mask:0xf\n\t"
        "v_add_f32_dpp %3, %3, %3 quad_perm:[2,3,0,1] row_mask:0xf bank_mask:0xf\n\t"
        "v_add_f32_dpp %0, %0, %0 row_half_mirror row_mask:0xf bank_mask:0xf\n\t"
        "v_add_f32_dpp %1, %1, %1 row_half_mirror row_mask:0xf bank_mask:0xf\n\t"
        "v_add_f32_dpp %2, %2, %2 row_half_mirror row_mask:0xf bank_mask:0xf\n\t"
        "v_add_f32_dpp %3, %3, %3 row_half_mirror row_mask:0xf bank_mask:0xf\n\t"
        "v_add_f32_dpp %0, %0, %0 row_mirror row_mask:0xf bank_mask:0xf\n\t"
        "v_add_f32_dpp %1, %1, %1 row_mirror row_mask:0xf bank_mask:0xf\n\t"
        "v_add_f32_dpp %2, %2, %2 row_mirror row_mask:0xf bank_mask:0xf\n\t"
        "v_add_f32_dpp %3, %3, %3 row_mirror row_mask:0xf bank_mask:0xf\n\t"
        "v_add_f32_dpp %0, %0, %0 row_bcast:15 row_mask:0xf bank_mask:0xf\n\t"
        "v_add_f32_dpp %1, %1, %1 row_bcast:15 row_mask:0xf bank_mask:0xf\n\t"
        "v_add_f32_dpp %2, %2, %2 row_bcast:15 row_mask:0xf bank_mask:0xf\n\t"
        "v_add_f32_dpp %3, %3, %3 row_bcast:15 row_mask:0xf bank_mask:0xf"
        : "+v"(p0), "+v"(p1), "+v"(p2), "+v"(p3));
}

// LDS-only barrier: drain LDS ops, sync waves. Does NOT drain vmcnt.
__device__ __forceinline__ void lds_barrier() {
    asm volatile("s_waitcnt lgkmcnt(0)\n\ts_barrier" ::: "memory");
}

__global__ __launch_bounds__(256, 1) void qlstm_kernel(
    const float* __restrict__ x,      // [B,T,F]
    const float* __restrict__ W_in,   // [H+F, 4] (row = float4)
    const float* __restrict__ b_in,   // [4]
    const float* __restrict__ Wq,     // [4,4,4]
    const float* __restrict__ bq,     // [4,4]
    const float* __restrict__ W_out,  // [4,H]
    const float* __restrict__ b_out,  // [H]
    float* __restrict__ out)          // [B*T*H] ++ [B*H] ++ [B*H]
{
    const int b = blockIdx.x;
    const int g = threadIdx.x;   // 0..255 — my h index
    const int w = g >> 6;        // wave 0..3
    const int l = g & 63;

    // Exchange: 8 half-wave aq partials per m. Stride 12 floats (48B):
    // b128-aligned, bank alias <=2-way (free). [slot][m][gi*4+w], 8..11 pad.
    __shared__ __align__(16) float partA[2][16][12];

    const float4* Win4 = (const float4*)W_in;

    float4 t4 = Win4[g];
    float wh[4] = {t4.x, t4.y, t4.z, t4.w};

    const bool has_x = (w < 2);
    float wx[4] = {0.f, 0.f, 0.f, 0.f};
    if (has_x) {
        float4 u4 = Win4[H_ + g];
        wx[0] = u4.x; wx[1] = u4.y; wx[2] = u4.z; wx[3] = u4.w;
    }

    // z' weights with the per-gate scale sk and the q-affine folded in:
    //   z'[k] = bo2[k] + sum_r q'[4k+r] * wo2[k][r],  q' = rcp(1+exp2(aq))
    const float sk[4] = {-SC1, -SC1, SC2, -SC1};
    float wo2[4][4];
    float bo2[4];
    {
        const float bo = b_out[g];
        float wos[4];
        float wsum = 0.f;
#pragma unroll
        for (int r = 0; r < 4; ++r) { wos[r] = W_out[r * H_ + g]; wsum += wos[r]; }
#pragma unroll
        for (int k = 0; k < 4; ++k) {
            bo2[k] = sk[k] * (bo + wsum);
#pragma unroll
            for (int r = 0; r < 4; ++r) wo2[k][r] = -2.0f * sk[k] * wos[r];
        }
    }

    float bin[4];
#pragma unroll
    for (int q = 0; q < 4; ++q) bin[q] = b_in[q];

    // Lane-distributed q-block (pre-scaled by SC2, b_in folded).
    const int m = l & 15, qk = m >> 2, qr = m & 3;
    float wql[4];
#pragma unroll
    for (int s = 0; s < 4; ++s) wql[s] = Wq[qk * 16 + s * 4 + qr];
    float bql = bq[qk * 4 + qr];
#pragma unroll
    for (int s = 0; s < 4; ++s) bql = fmaf(bin[s], wql[s], bql);
    bql *= SC2;
#pragma unroll
    for (int s = 0; s < 4; ++s) wql[s] *= SC2;
    // Bias contributed exactly once: wave 0's lower half-group (lanes 16-31
    // write gi=0; lanes 0-15 also carry it but never write).
    const float bqlw = (w == 0 && l < 32) ? bql : 0.0f;

    // My write slot: groups lanes 16-31 (gi=0, r0+r1) / 48-63 (gi=1, r2+r3).
    const int gi = l >> 5;
    float* const wslot0 = &partA[0][m][gi * 4 + w];
    float* const wslot1 = &partA[1][m][gi * 4 + w];

    // Recurrent state: tau = tanh(c), C = SC2*c, owh = o*wh.
    float tau = 0.f, C = 0.f;
    float owh0 = 0.f, owh1 = 0.f, owh2 = 0.f, owh3 = 0.f;

    const float* xp = x + (size_t)b * T_ * F_ + g;
    float xq0 = 0.f, xq1 = 0.f, xq2 = 0.f, xq3 = 0.f;
    float xv1 = 0.f;
    if (has_x) {
        const float xv0 = xp[0];
        xv1 = xp[F_];
        xq0 = xv0 * wx[0]; xq1 = xv0 * wx[1];
        xq2 = xv0 * wx[2]; xq3 = xv0 * wx[3];
    }

    float* outp = out + (size_t)b * T_ * H_ + g;
    float o_last = 0.f;

#define STEP(t_, slot_)                                                        \
    {                                                                          \
        float p0 = fmaf(tau, owh0, xq0);                                       \
        float p1 = fmaf(tau, owh1, xq1);                                       \
        float p2 = fmaf(tau, owh2, xq2);                                       \
        float p3 = fmaf(tau, owh3, xq3);                                       \
        tree4_5(p0, p1, p2, p3);                                               \
        /* half-wave aq contribution (valid in groups 16-31 / 48-63) */        \
        float u = fmaf(p0, wql[0], bqlw);                                      \
        const float vv = fmaf(p3, wql[3], p2 * wql[2]);                        \
        u = fmaf(p1, wql[1], u);                                               \
        const float aqw = u + vv;                                              \
        if (l & 16) *((slot_) ? wslot1 : wslot0) = aqw;                        \
        lds_barrier();                                                         \
        const float4 a0 = *(const float4*)&partA[slot_][m][0];                 \
        const float4 a1 = *(const float4*)&partA[slot_][m][4];                 \
        /* window filler: next step's x products + prefetch (y-independent) */ \
        if (has_x) {                                                           \
            xq0 = xv1 * wx[0]; xq1 = xv1 * wx[1];                              \
            xq2 = xv1 * wx[2]; xq3 = xv1 * wx[3];                              \
            int tn = (t_) + 2; if (tn >= T_) tn = T_ - 1;                      \
            xv1 = xp[(size_t)tn * F_];                                         \
        }                                                                      \
        /* packed combine of 8 partials: 3 pk_add + 1 add */                   \
        const f2 u0 = mk2(a0.x, a0.y) + mk2(a0.z, a0.w);                       \
        const f2 u1 = mk2(a1.x, a1.y) + mk2(a1.z, a1.w);                       \
        const f2 us = u0 + u1;                                                 \
        const float aq = us.x + us.y;                                          \
        const float qp = rcp_f(1.0f + exp2_f(aq));   /* q' (affine folded) */  \
        /* spine-priority: k=2 (g-gate) first -> exp2(E2) issues earliest */   \
        const float qs8  = rl(qp, 8),  qs9  = rl(qp, 9);                       \
        const float qs10 = rl(qp, 10), qs11 = rl(qp, 11);                      \
        const float zp2 = fmaf(qs11, wo2[2][3], fmaf(qs10, wo2[2][2],          \
                          fmaf(qs9,  wo2[2][1], fmaf(qs8,  wo2[2][0],          \
                               bo2[2]))));                                     \
        const float E2 = exp2_f(zp2);                                          \
        const float qs0 = rl(qp, 0), qs1 = rl(qp, 1);                          \
        const float qs2 = rl(qp, 2), qs3 = rl(qp, 3);                          \
        const float zp0 = fmaf(qs3, wo2[0][3], fmaf(qs2, wo2[0][2],            \
                          fmaf(qs1, wo2[0][1], fmaf(qs0, wo2[0][0],            \
                               bo2[0]))));                                     \
        const float e0 = exp2_f(zp0);                                          \
        const float qs4 = rl(qp, 4), qs5 = rl(qp, 5);                          \
        const float qs6 = rl(qp, 6), qs7 = rl(qp, 7);                          \
        const float zp1 = fmaf(qs7, wo2[1][3], fmaf(qs6, wo2[1][2],            \
                          fmaf(qs5, wo2[1][1], fmaf(qs4, wo2[1][0],            \
                               bo2[1]))));                                     \
        const float e1 = exp2_f(zp1);                                          \
        const float u2   = 1.0f + E2;                                          \
        const float den  = fmaf(e0, u2, u2);         /* (1+e0)(1+E2) */        \
        const float num2 = fmaf(SC2, E2, -SC2);      /* SC2*(E2-1) */          \
        const float IG2  = num2 * rcp_f(den);                                  \
        const float fg   = rcp_f(1.0f + e1);                                   \
        C = fmaf(fg, C, IG2);                                                  \
        const float Ec = exp2_f(C);   /* issued before the o-block */          \
        const float qs12 = rl(qp, 12), qs13 = rl(qp, 13);                      \
        const float qs14 = rl(qp, 14), qs15 = rl(qp, 15);                      \
        const float zp3 = fmaf(qs15, wo2[3][3], fmaf(qs14, wo2[3][2],          \
                          fmaf(qs13, wo2[3][1], fmaf(qs12, wo2[3][0],          \
                               bo2[3]))));                                     \
        const float e3 = exp2_f(zp3);                                          \
        const float o  = rcp_f(1.0f + e3);                                     \
        owh0 = o * wh[0]; owh1 = o * wh[1];                                    \
        owh2 = o * wh[2]; owh3 = o * wh[3];                                    \
        tau = (Ec - 1.0f) * rcp_f(1.0f + Ec);                                  \
        o_last = o;                                                            \
        outp[(size_t)(t_) * H_] = tau * o;   /* store off-chain */             \
    }

    for (int t = 0; t < T_; t += 4) {
        STEP(t, 0);
        STEP(t + 1, 1);
        STEP(t + 2, 0);
        STEP(t + 3, 1);
    }
#undef STEP

    float* hT = out + (size_t)B_ * T_ * H_;
    hT[(size_t)b * H_ + g] = tau * o_last;
    hT[(size_t)B_ * H_ + (size_t)b * H_ + g] = C * ISC2;
}

extern "C" void kernel_launch(void* const* d_in, const int* in_sizes, int n_in,
                              void* d_out, int out_size, void* d_ws, size_t ws_size,
                              hipStream_t stream) {
    const float* x     = (const float*)d_in[0];
    const float* W_in  = (const float*)d_in[1];
    const float* b_in  = (const float*)d_in[2];
    const float* Wq    = (const float*)d_in[3];
    const float* bq    = (const float*)d_in[4];
    const float* W_out = (const float*)d_in[5];
    const float* b_out = (const float*)d_in[6];
    float* out = (float*)d_out;

    qlstm_kernel<<<dim3(B_), dim3(256), 0, stream>>>(
        x, W_in, b_in, Wq, bq, W_out, b_out, out);
}

// Round 10
// 367.131 us; speedup vs baseline: 1.0163x; 1.0163x over previous
//
#include <hip/hip_runtime.h>

// QLSTM recurrence on MI355X — round 11 (resubmit; round-9's bench was an
// infra container failure, kernel never ran — this is a byte-identical revert
// of the round-9 kernel that already passed at 232.9 us/dispatch).
//
// FLOOR DECLARATION (per r8 pre-commit, confirmed by r9 neutral + r10
// regression): this kernel is at the structural latency floor of the
// 512-step serial recurrence, ~1090 cyc/step:
//   - exchange RT ~250 cyc: barrier+LDS round trip; flag-poll (r8) and
//     depth-trades (r10) are not cheaper; replication (r4) is 2x worse.
//   - trans spine ~250-300 cyc: 6 dependent exp2/rcp + readlane + z-dots;
//     reordering is neutral (r9) => latency- not issue-dominated.
//   - issue ~430 cyc @ 39% VALUBusy: further trims neutral (r9).
//   - occupancy pinned at 1 wave/SIMD: 256 chains = 256 CUs; dual-chain
//     co-location halves active CUs for the same per-step wall (no gain).
// Counters: HBM 9%, VALU 39% — latency-bound, not a memory/compute roofline.
//
// Structure: 4 waves / 4 SIMDs, lane g owns h[g], fused-DPP 6-level tree,
// per-wave aq-dot pre-barrier, raw lgkm-only barrier, q-affine folded
// z-weights, tau/owh split, merged-rcp pre-scaled gates, spine-priority
// ordering, x window filler, unroll x4.

#define B_ 256
#define T_ 512
#define F_ 128
#define H_ 256

#define SC1 1.442695041f    // log2(e)
#define SC2 2.885390082f    // 2*log2(e)
#define ISC2 0.3465735903f  // 1/SC2

typedef float f2 __attribute__((ext_vector_type(2)));

__device__ __forceinline__ float rcp_f(float x)  { return __builtin_amdgcn_rcpf(x); }
__device__ __forceinline__ float exp2_f(float x) { return __builtin_amdgcn_exp2f(x); }

__device__ __forceinline__ float rl(float v, int lane) {
    return __int_as_float(__builtin_amdgcn_readlane(__float_as_int(v), lane));
}

// Fused 64-lane sum of 4 independent values; results valid at lanes 48-63
// (row 3 accumulates the full sum after row_bcast15 + row_bcast31).
// 6 levels x 4 interleaved chains: DPP consumer >=4 instrs from producer
// (VALU->DPP hazard covered by construction; s_nop 1 guards the entry).
__device__ __forceinline__ void tree4(float& p0, float& p1, float& p2, float& p3) {
    asm volatile(
        "s_nop 1\n\t"
        "v_add_f32_dpp %0, %0, %0 quad_perm:[1,0,3,2] row_mask:0xf bank_mask:0xf\n\t"
        "v_add_f32_dpp %1, %1, %1 quad_perm:[1,0,3,2] row_mask:0xf bank_mask:0xf\n\t"
        "v_add_f32_dpp %2, %2, %2 quad_perm:[1,0,3,2] row_mask:0xf bank_mask:0xf\n\t"
        "v_add_f32_dpp %3, %3, %3 quad_perm:[1,0,3,2] row_mask:0xf bank_mask:0xf\n\t"
        "v_add_f32_dpp %0, %0, %0 quad_perm:[2,3,0,1] row_mask:0xf bank_mask:0xf\n\t"
        "v_add_f32_dpp %1, %1, %1 quad_perm:[2,3,0,1] row_mask:0xf bank_mask:0xf\n\t"
        "v_add_f32_dpp %2, %2, %2 quad_perm:[2,3,0,1] row_mask:0xf bank_mask:0xf\n\t"
        "v_add_f32_dpp %3, %3, %3 quad_perm:[2,3,0,1] row_mask:0xf bank_mask:0xf\n\t"
        "v_add_f32_dpp %0, %0, %0 row_half_mirror row_mask:0xf bank_mask:0xf\n\t"
        "v_add_f32_dpp %1, %1, %1 row_half_mirror row_mask:0xf bank_mask:0xf\n\t"
        "v_add_f32_dpp %2, %2, %2 row_half_mirror row_mask:0xf bank_mask:0xf\n\t"
        "v_add_f32_dpp %3, %3, %3 row_half_mirror row_mask:0xf bank_mask:0xf\n\t"
        "v_add_f32_dpp %0, %0, %0 row_mirror row_mask:0xf bank_mask:0xf\n\t"
        "v_add_f32_dpp %1, %1, %1 row_mirror row_mask:0xf bank_mask:0xf\n\t"
        "v_add_f32_dpp %2, %2, %2 row_mirror row_mask:0xf bank_mask:0xf\n\t"
        "v_add_f32_dpp %3, %3, %3 row_mirror row_mask:0xf bank_mask:0xf\n\t"
        "v_add_f32_dpp %0, %0, %0 row_bcast:15 row_mask:0xf bank_mask:0xf\n\t"
        "v_add_f32_dpp %1, %1, %1 row_bcast:15 row_mask:0xf bank_mask:0xf\n\t"
        "v_add_f32_dpp %2, %2, %2 row_bcast:15 row_mask:0xf bank_mask:0xf\n\t"
        "v_add_f32_dpp %3, %3, %3 row_bcast:15 row_mask:0xf bank_mask:0xf\n\t"
        "v_add_f32_dpp %0, %0, %0 row_bcast:31 row_mask:0xf bank_mask:0xf\n\t"
        "v_add_f32_dpp %1, %1, %1 row_bcast:31 row_mask:0xf bank_mask:0xf\n\t"
        "v_add_f32_dpp %2, %2, %2 row_bcast:31 row_mask:0xf bank_mask:0xf\n\t"
        "v_add_f32_dpp %3, %3, %3 row_bcast:31 row_mask:0xf bank_mask:0xf"
        : "+v"(p0), "+v"(p1), "+v"(p2), "+v"(p3));
}

// LDS-only barrier: drain LDS ops, sync waves. Does NOT drain vmcnt.
__device__ __forceinline__ void lds_barrier() {
    asm volatile("s_waitcnt lgkmcnt(0)\n\ts_barrier" ::: "memory");
}

__global__ __launch_bounds__(256, 1) void qlstm_kernel(
    const float* __restrict__ x,      // [B,T,F]
    const float* __restrict__ W_in,   // [H+F, 4] (row = float4)
    const float* __restrict__ b_in,   // [4]
    const float* __restrict__ Wq,     // [4,4,4]
    const float* __restrict__ bq,     // [4,4]
    const float* __restrict__ W_out,  // [4,H]
    const float* __restrict__ b_out,  // [H]
    float* __restrict__ out)          // [B*T*H] ++ [B*H] ++ [B*H]
{
    const int b = blockIdx.x;
    const int g = threadIdx.x;   // 0..255 — my h index
    const int w = g >> 6;        // wave 0..3
    const int l = g & 63;

    // Exchange: per-wave aq contributions. partA[slot][m][w], 512 B.
    __shared__ __align__(16) float partA[2][16][4];

    const float4* Win4 = (const float4*)W_in;

    float4 t4 = Win4[g];
    float wh[4] = {t4.x, t4.y, t4.z, t4.w};

    const bool has_x = (w < 2);
    float wx[4] = {0.f, 0.f, 0.f, 0.f};
    if (has_x) {
        float4 u4 = Win4[H_ + g];
        wx[0] = u4.x; wx[1] = u4.y; wx[2] = u4.z; wx[3] = u4.w;
    }

    // z' weights with the per-gate scale sk and the q-affine folded in:
    //   z'[k] = bo2[k] + sum_r q'[4k+r] * wo2[k][r],  q' = rcp(1+exp2(aq))
    const float sk[4] = {-SC1, -SC1, SC2, -SC1};
    float wo2[4][4];
    float bo2[4];
    {
        const float bo = b_out[g];
        float wos[4];
        float wsum = 0.f;
#pragma unroll
        for (int r = 0; r < 4; ++r) { wos[r] = W_out[r * H_ + g]; wsum += wos[r]; }
#pragma unroll
        for (int k = 0; k < 4; ++k) {
            bo2[k] = sk[k] * (bo + wsum);
#pragma unroll
            for (int r = 0; r < 4; ++r) wo2[k][r] = -2.0f * sk[k] * wos[r];
        }
    }

    float bin[4];
#pragma unroll
    for (int q = 0; q < 4; ++q) bin[q] = b_in[q];

    // Lane-distributed q-block (pre-scaled by SC2, b_in folded).
    const int m = l & 15, qk = m >> 2, qr = m & 3;
    float wql[4];
#pragma unroll
    for (int s = 0; s < 4; ++s) wql[s] = Wq[qk * 16 + s * 4 + qr];
    float bql = bq[qk * 4 + qr];
#pragma unroll
    for (int s = 0; s < 4; ++s) bql = fmaf(bin[s], wql[s], bql);
    bql *= SC2;
#pragma unroll
    for (int s = 0; s < 4; ++s) wql[s] *= SC2;
    const float bqlw = (w == 0) ? bql : 0.0f;   // bias added by wave 0 only

    // Recurrent state: tau = tanh(c), C = SC2*c, owh = o*wh.
    float tau = 0.f, C = 0.f;
    float owh0 = 0.f, owh1 = 0.f, owh2 = 0.f, owh3 = 0.f;

    const float* xp = x + (size_t)b * T_ * F_ + g;
    float xq0 = 0.f, xq1 = 0.f, xq2 = 0.f, xq3 = 0.f;
    float xv1 = 0.f;
    if (has_x) {
        const float xv0 = xp[0];
        xv1 = xp[F_];
        xq0 = xv0 * wx[0]; xq1 = xv0 * wx[1];
        xq2 = xv0 * wx[2]; xq3 = xv0 * wx[3];
    }

    float* outp = out + (size_t)b * T_ * H_ + g;
    float o_last = 0.f;

#define STEP(t_, slot_)                                                        \
    {                                                                          \
        float p0 = fmaf(tau, owh0, xq0);                                       \
        float p1 = fmaf(tau, owh1, xq1);                                       \
        float p2 = fmaf(tau, owh2, xq2);                                       \
        float p3 = fmaf(tau, owh3, xq3);                                       \
        tree4(p0, p1, p2, p3);                                                 \
        /* per-wave aq contribution; valid at lanes 48-63 (m = l-48) */        \
        float u = fmaf(p0, wql[0], bqlw);                                      \
        const float vv = fmaf(p3, wql[3], p2 * wql[2]);                        \
        u = fmaf(p1, wql[1], u);                                               \
        const float aqw = u + vv;                                              \
        if (l >= 48) partA[slot_][m][w] = aqw;                                 \
        lds_barrier();                                                         \
        const float4 a = *(const float4*)&partA[slot_][m][0];                  \
        /* window filler: next step's x products + prefetch (y-independent) */ \
        if (has_x) {                                                           \
            xq0 = xv1 * wx[0]; xq1 = xv1 * wx[1];                              \
            xq2 = xv1 * wx[2]; xq3 = xv1 * wx[3];                              \
            int tn = (t_) + 2; if (tn >= T_) tn = T_ - 1;                      \
            xv1 = xp[(size_t)tn * F_];                                         \
        }                                                                      \
        /* packed combine: 1 pk_add + 1 add */                                 \
        f2 clo; clo.x = a.x; clo.y = a.y;                                      \
        f2 chi; chi.x = a.z; chi.y = a.w;                                      \
        const f2 cs = clo + chi;                                               \
        const float aq = cs.x + cs.y;                                          \
        const float qp = rcp_f(1.0f + exp2_f(aq));   /* q' (affine folded) */  \
        /* spine-priority: k=2 (g-gate) first -> exp2(E2) issues earliest */   \
        const float qs8  = rl(qp, 8),  qs9  = rl(qp, 9);                       \
        const float qs10 = rl(qp, 10), qs11 = rl(qp, 11);                      \
        const float zp2 = fmaf(qs11, wo2[2][3], fmaf(qs10, wo2[2][2],          \
                          fmaf(qs9,  wo2[2][1], fmaf(qs8,  wo2[2][0],          \
                               bo2[2]))));                                     \
        const float E2 = exp2_f(zp2);                                          \
        const float qs0 = rl(qp, 0), qs1 = rl(qp, 1);                          \
        const float qs2 = rl(qp, 2), qs3 = rl(qp, 3);                          \
        const float zp0 = fmaf(qs3, wo2[0][3], fmaf(qs2, wo2[0][2],            \
                          fmaf(qs1, wo2[0][1], fmaf(qs0, wo2[0][0],            \
                               bo2[0]))));                                     \
        const float e0 = exp2_f(zp0);                                          \
        const float qs4 = rl(qp, 4), qs5 = rl(qp, 5);                          \
        const float qs6 = rl(qp, 6), qs7 = rl(qp, 7);                          \
        const float zp1 = fmaf(qs7, wo2[1][3], fmaf(qs6, wo2[1][2],            \
                          fmaf(qs5, wo2[1][1], fmaf(qs4, wo2[1][0],            \
                               bo2[1]))));                                     \
        const float e1 = exp2_f(zp1);                                          \
        const float u2   = 1.0f + E2;                                          \
        const float den  = fmaf(e0, u2, u2);         /* (1+e0)(1+E2) */        \
        const float num2 = fmaf(SC2, E2, -SC2);      /* SC2*(E2-1) */          \
        const float IG2  = num2 * rcp_f(den);                                  \
        const float fg   = rcp_f(1.0f + e1);                                   \
        C = fmaf(fg, C, IG2);                                                  \
        const float Ec = exp2_f(C);   /* issued before the o-block */          \
        const float qs12 = rl(qp, 12), qs13 = rl(qp, 13);                      \
        const float qs14 = rl(qp, 14), qs15 = rl(qp, 15);                      \
        const float zp3 = fmaf(qs15, wo2[3][3], fmaf(qs14, wo2[3][2],          \
                          fmaf(qs13, wo2[3][1], fmaf(qs12, wo2[3][0],          \
                               bo2[3]))));                                     \
        const float e3 = exp2_f(zp3);                                          \
        const float o  = rcp_f(1.0f + e3);                                     \
        owh0 = o * wh[0]; owh1 = o * wh[1];                                    \
        owh2 = o * wh[2]; owh3 = o * wh[3];                                    \
        tau = (Ec - 1.0f) * rcp_f(1.0f + Ec);                                  \
        o_last = o;                                                            \
        outp[(size_t)(t_) * H_] = tau * o;   /* store off-chain */             \
    }

    for (int t = 0; t < T_; t += 4) {
        STEP(t, 0);
        STEP(t + 1, 1);
        STEP(t + 2, 0);
        STEP(t + 3, 1);
    }
#undef STEP

    float* hT = out + (size_t)B_ * T_ * H_;
    hT[(size_t)b * H_ + g] = tau * o_last;
    hT[(size_t)B_ * H_ + (size_t)b * H_ + g] = C * ISC2;
}

extern "C" void kernel_launch(void* const* d_in, const int* in_sizes, int n_in,
                              void* d_out, int out_size, void* d_ws, size_t ws_size,
                              hipStream_t stream) {
    const float* x     = (const float*)d_in[0];
    const float* W_in  = (const float*)d_in[1];
    const float* b_in  = (const float*)d_in[2];
    const float* Wq    = (const float*)d_in[3];
    const float* bq    = (const float*)d_in[4];
    const float* W_out = (const float*)d_in[5];
    const float* b_out = (const float*)d_in[6];
    float* out = (float*)d_out;

    qlstm_kernel<<<dim3(B_), dim3(256), 0, stream>>>(
        x, W_in, b_in, Wq, bq, W_out, b_out, out);
}